// Round 1
// 212.990 us; speedup vs baseline: 1.0465x; 1.0465x over previous
//
#include <hip/hip_runtime.h>
#include <math.h>

#define NORB 13
#define NORB2 (NORB * NORB)
#define GB 16                  // b-atoms per group: strip = 13 x 208 complex
#define KSPLIT 2               // k-chunks per bin
#define MAXE 128               // per-bin entry capacity (mean ~4, Poisson tail << 128)
#define NTHR 256

typedef float fx2 __attribute__((ext_vector_type(2)));

// block id per orbital index for L_LIST=[0,0,1,1,2] -> sizes 1,1,3,3,5
__device__ __forceinline__ int blk_of(int p) {
    return p < 1 ? 0 : (p < 2 ? 1 : (p < 5 ? 2 : (p < 8 ? 3 : 4)));
}
__device__ __forceinline__ float ffac(int p, int q) {
    int bp = blk_of(p), bq = blk_of(q);
    return bp < bq ? 1.0f : (bp == bq ? 0.5f : 0.0f);
}

// One WG per (a, b-group, k-chunk). Builds its own sorted entry list from the
// (tiny, L2-hot) edge list, then accumulates each 13x13 block in registers and
// stores straight to global. No LDS data path, no barriers in the k-loop.
__global__ void __launch_bounds__(NTHR)
k_fused(const float* __restrict__ hopping,
        const float* __restrict__ onsite,
        const float* __restrict__ kpoints,
        const float* __restrict__ cell_shift,
        const int* __restrict__ edge_index,
        float* __restrict__ out,
        int N, int E, int K, int ld, int es, int ngroups) {
    int g  = blockIdx.x % ngroups;
    int a  = (blockIdx.x / ngroups) % N;
    int kc = blockIdx.x / (ngroups * N);
    int kch = (K + KSPLIT - 1) / KSPLIT;
    int k0 = kc * kch, k1 = min(K, k0 + kch);
    int tid = threadIdx.x;
    int b0 = g * GB;

    __shared__ int cnt[GB + 1];   // counts -> offsets
    __shared__ int cur[GB];       // placement cursors
    __shared__ int list[MAXE];    // (e<<1)|rev, counting-sorted by b-atom in group

    if (tid <= GB) cnt[tid] = 0;
    __syncthreads();

    // pass 1: count entries per b-atom slot (forward a->b and reverse b->a)
    for (int e = tid; e < E; e += NTHR) {
        int ie = edge_index[e], je = edge_index[E + e];
        if (ie == a && (je >> 4) == g) atomicAdd(&cnt[je & 15], 1);
        if (je == a && (ie >> 4) == g) atomicAdd(&cnt[ie & 15], 1);
    }
    __syncthreads();
    if (tid == 0) {               // 16-element serial prefix: trivial
        int run = 0;
        for (int i = 0; i < GB; ++i) { int c = cnt[i]; cnt[i] = run; cur[i] = run; run += c; }
        cnt[GB] = run;
    }
    __syncthreads();
    // pass 2: place (grouped by i so the unrolled i-loop gets contiguous runs)
    for (int e = tid; e < E; e += NTHR) {
        int ie = edge_index[e], je = edge_index[E + e];
        if (ie == a && (je >> 4) == g) {
            int pos = atomicAdd(&cur[je & 15], 1);
            if (pos < MAXE) list[pos] = (e << 1);          // forward: phase * hopF
        }
        if (je == a && (ie >> 4) == g) {
            int pos = atomicAdd(&cur[ie & 15], 1);
            if (pos < MAXE) list[pos] = (e << 1) | 1;      // reverse: conj * hopF^T
        }
    }
    __syncthreads();

    // hoist offsets to SGPRs: scalar loop bounds -> uniform s_cbranch loops
    int offs[GB + 1];
    #pragma unroll
    for (int i = 0; i <= GB; ++i) offs[i] = __builtin_amdgcn_readfirstlane(cnt[i]);

    if (tid >= NORB2) return;     // no barriers below; inactive waves retire
    int p = tid / NORB, q = tid - p * NORB;
    float fpq = ffac(p, q), fqp = ffac(q, p);
    int idxF = p * NORB + q, idxR = q * NORB + p;

    // hermitized onsite value for the diagonal block (k-independent, real)
    bool dwg = (a >= b0) && (a < b0 + GB);
    int idiag = a - b0;
    float onx = 0.f;
    if (dwg) {
        const float* on = onsite + (size_t)a * NORB2;
        onx = on[idxF] * fpq + on[idxR] * fqp;
    }

    for (int k = k0; k < k1; ++k) {
        float kx = kpoints[3 * k], ky = kpoints[3 * k + 1], kz = kpoints[3 * k + 2];
        // complex-unit index of this thread's row/col base in out[k]
        size_t rowc = ((size_t)(k * ld + a * NORB + p)) * ld + (size_t)b0 * NORB + q;

        #pragma unroll
        for (int i = 0; i < GB; ++i) {
            float ax = (dwg && i == idiag) ? onx : 0.f;
            float ay = 0.f;
            int itend = offs[i + 1];
            for (int it = offs[i]; it < itend; ++it) {
                int ent = __builtin_amdgcn_readfirstlane(list[it]);  // uniform
                int e = ent >> 1;
                const float* cs = cell_shift + 3 * (size_t)e;
                float d = kx * cs[0] + ky * cs[1] + kz * cs[2];
                float s, c;
                __sincosf(-6.2831853071795864f * d, &s, &c);  // exp(-i*2pi*d)=c+i*s
                const float* h = hopping + (size_t)e * NORB2;
                float hv, im;
                if (ent & 1) { hv = h[idxR] * fqp; im = -s; }   // reverse: conj, transpose
                else         { hv = h[idxF] * fpq; im =  s; }
                ax += c * hv;
                ay += im * hv;
            }
            if (b0 + i < N) {
                if (es == 2) {
                    fx2* o2 = (fx2*)out;
                    o2[rowc + (size_t)i * NORB] = (fx2){ax, ay};  // 8B store, imm offset
                } else {
                    out[rowc + (size_t)i * NORB] = ax;
                }
            }
        }
    }
}

extern "C" void kernel_launch(void* const* d_in, const int* in_sizes, int n_in,
                              void* d_out, int out_size, void* d_ws, size_t ws_size,
                              hipStream_t stream) {
    const float* hopping    = (const float*)d_in[0];
    const float* onsite     = (const float*)d_in[1];
    const float* kpoints    = (const float*)d_in[2];
    const float* cell_shift = (const float*)d_in[3];
    const int*   edge_index = (const int*)d_in[4];
    float* out = (float*)d_out;

    int E = in_sizes[0] / NORB2;   // 2048
    int N = in_sizes[1] / NORB2;   // 128
    int K = in_sizes[2] / 3;       // 16
    int ld = N * NORB;             // 1664
    int ngroups = (N + GB - 1) / GB;   // 8

    size_t full = (size_t)K * ld * ld * 2;
    int es = ((size_t)out_size >= full) ? 2 : 1;

    int nwg = N * ngroups * KSPLIT;    // 2048 WGs, exactly 8/CU, 32 waves/CU
    k_fused<<<nwg, NTHR, 0, stream>>>(hopping, onsite, kpoints, cell_shift,
                                      edge_index, out, N, E, K, ld, es, ngroups);
}

// Round 2
// 207.942 us; speedup vs baseline: 1.0719x; 1.0243x over previous
//
#include <hip/hip_runtime.h>
#include <math.h>

#define NORB 13
#define NORB2 (NORB * NORB)
#define GB 16                  // b-atoms per group; strip row = 208 complex = 1664 B
#define NCOL (GB * NORB)       // 208 columns per strip
#define KSPLIT 2               // k-chunks per bin
#define MAXE 128               // per-bin entry capacity (mean ~4)
#define NTHR 256

typedef float fx2 __attribute__((ext_vector_type(2)));

// block id per orbital index for L_LIST=[0,0,1,1,2] -> sizes 1,1,3,3,5
__device__ __forceinline__ int blk_of(int p) {
    return p < 1 ? 0 : (p < 2 ? 1 : (p < 5 ? 2 : (p < 8 ? 3 : 4)));
}
__device__ __forceinline__ float bfac(int bp, int bq) {
    return bp < bq ? 1.0f : (bp == bq ? 0.5f : 0.0f);
}

// One WG per (a, b-group, k-chunk). Thread = one strip COLUMN c = i*13+q;
// accumulates all 13 rows in registers, stores each row as a wave-dense
// contiguous run (full 64B lines only -> no partial-sector write traffic).
__global__ void __launch_bounds__(NTHR)
k_fused(const float* __restrict__ hopping,
        const float* __restrict__ onsite,
        const float* __restrict__ kpoints,
        const float* __restrict__ cell_shift,
        const int* __restrict__ edge_index,
        float* __restrict__ out,
        int N, int E, int K, int ld, int es, int ngroups) {
    int g  = blockIdx.x % ngroups;
    int a  = (blockIdx.x / ngroups) % N;
    int kc = blockIdx.x / (ngroups * N);
    int kch = (K + KSPLIT - 1) / KSPLIT;
    int k0 = kc * kch, k1 = min(K, k0 + kch);
    int tid = threadIdx.x;
    int b0 = g * GB;

    __shared__ int ecnt;
    __shared__ int list[MAXE];   // (e<<5) | (b_slot<<1) | rev

    if (tid == 0) ecnt = 0;
    __syncthreads();

    // scan tiny edge list (16 KB, L1-hot) for entries hitting this (a,g) bin
    for (int e = tid; e < E; e += NTHR) {
        int ie = edge_index[e], je = edge_index[E + e];
        if (ie == a && (je >> 4) == g) {
            int pos = atomicAdd(&ecnt, 1);
            if (pos < MAXE) list[pos] = (e << 5) | ((je & 15) << 1);       // fwd
        }
        if (je == a && (ie >> 4) == g) {
            int pos = atomicAdd(&ecnt, 1);
            if (pos < MAXE) list[pos] = (e << 5) | ((ie & 15) << 1) | 1;   // rev
        }
    }
    __syncthreads();
    int nent = min(__builtin_amdgcn_readfirstlane(ecnt), MAXE);

    // broadcast list into registers: lane l of every wave holds list[l];
    // per-entry access becomes one v_readlane (no LDS latency in k-loop)
    int lane = tid & 63;
    int myent = (lane < nent) ? list[lane] : 0;

    int c = tid;                              // strip column
    if (c >= NCOL || g * NCOL + c >= ld) return;
    int i_c = c / NORB;                       // b-slot of this column
    int q   = c - i_c * NORB;                 // orbital col within block
    int bq  = blk_of(q);
    bool diagact = (b0 + i_c == a);
    const float* on = onsite + (size_t)a * NORB2;

    for (int k = k0; k < k1; ++k) {
        float kx = kpoints[3 * k], ky = kpoints[3 * k + 1], kz = kpoints[3 * k + 2];

        // init accumulators with hermitized onsite (diagonal block only, real)
        float ax[NORB], ay[NORB];
        #pragma unroll
        for (int p = 0; p < NORB; ++p) {
            float v = 0.f;
            if (diagact) {
                int bp = blk_of(p);           // compile-time per unrolled p
                v = on[p * NORB + q] * bfac(bp, bq)
                  + on[q * NORB + p] * bfac(bq, bp);
            }
            ax[p] = v; ay[p] = 0.f;
        }

        for (int it = 0; it < nent; ++it) {
            int ent = (it < 64) ? __builtin_amdgcn_readlane(myent, it) : list[it];
            int e = ent >> 5;
            int islot = (ent >> 1) & 15;
            int rev = ent & 1;
            const float* cs = cell_shift + 3 * (size_t)e;
            float d = kx * cs[0] + ky * cs[1] + kz * cs[2];
            float s, cc;
            __sincosf(-6.2831853071795864f * d, &s, &cc);   // exp(-i*2pi*d)=cc+i*s
            float sv = rev ? -s : s;                        // conj for reverse
            if (i_c == islot) {                             // 13 lanes active
                const float* h = hopping + (size_t)e * NORB2;
                if (rev) {
                    #pragma unroll
                    for (int p = 0; p < NORB; ++p) {
                        float hv = h[q * NORB + p] * bfac(bq, blk_of(p));
                        ax[p] += cc * hv; ay[p] += sv * hv;
                    }
                } else {
                    #pragma unroll
                    for (int p = 0; p < NORB; ++p) {
                        float hv = h[p * NORB + q] * bfac(blk_of(p), bq);
                        ax[p] += cc * hv; ay[p] += sv * hv;
                    }
                }
            }
        }

        // store: per p, lanes 0..207 write 1664 contiguous bytes (64B-aligned)
        size_t base = ((size_t)(k * ld + a * NORB)) * ld + (size_t)g * NCOL + c;
        if (es == 2) {
            fx2* o2 = (fx2*)out;
            #pragma unroll
            for (int p = 0; p < NORB; ++p)
                o2[base + (size_t)p * ld] = (fx2){ax[p], ay[p]};
        } else {
            #pragma unroll
            for (int p = 0; p < NORB; ++p)
                out[base + (size_t)p * ld] = ax[p];
        }
    }
}

extern "C" void kernel_launch(void* const* d_in, const int* in_sizes, int n_in,
                              void* d_out, int out_size, void* d_ws, size_t ws_size,
                              hipStream_t stream) {
    const float* hopping    = (const float*)d_in[0];
    const float* onsite     = (const float*)d_in[1];
    const float* kpoints    = (const float*)d_in[2];
    const float* cell_shift = (const float*)d_in[3];
    const int*   edge_index = (const int*)d_in[4];
    float* out = (float*)d_out;

    int E = in_sizes[0] / NORB2;   // 2048
    int N = in_sizes[1] / NORB2;   // 128
    int K = in_sizes[2] / 3;       // 16
    int ld = N * NORB;             // 1664
    int ngroups = (N + GB - 1) / GB;   // 8

    size_t full = (size_t)K * ld * ld * 2;
    int es = ((size_t)out_size >= full) ? 2 : 1;

    int nwg = N * ngroups * KSPLIT;    // 2048 WGs
    k_fused<<<nwg, NTHR, 0, stream>>>(hopping, onsite, kpoints, cell_shift,
                                      edge_index, out, N, E, K, ld, es, ngroups);
}